// Round 2
// baseline (667.912 us; speedup 1.0000x reference)
//
#include <hip/hip_runtime.h>

#define NN 10000
#define NE 640000
#define D 128
#define NF (NN * D)

// ---------------- CSR build ----------------

__global__ void zero_cnt_kernel(int* __restrict__ cnt) {
    int i = blockIdx.x * 256 + threadIdx.x;
    if (i < NN) cnt[i] = 0;
}

__global__ void edge_prep_kernel(const int* __restrict__ ei, const float* __restrict__ conf,
                                 float* __restrict__ ew, int* __restrict__ cnt) {
    int e = blockIdx.x * 256 + threadIdx.x;
    if (e >= NE) return;
    int s = ei[e];
    int d = ei[NE + e];
    ew[e] = expf(-fabsf(conf[s] - conf[d]));
    atomicAdd(&cnt[d], 1);
}

__global__ void scan_kernel(const int* __restrict__ cnt, int* __restrict__ row_ptr,
                            int* __restrict__ cursor) {
    __shared__ int lds[256];
    int t = threadIdx.x;
    const int CH = (NN + 255) / 256;  // 40
    int base = t * CH;
    int s = 0;
    for (int i = 0; i < CH; i++) {
        int idx = base + i;
        if (idx < NN) s += cnt[idx];
    }
    lds[t] = s;
    __syncthreads();
    for (int off = 1; off < 256; off <<= 1) {
        int v = (t >= off) ? lds[t - off] : 0;
        __syncthreads();
        lds[t] += v;
        __syncthreads();
    }
    int run = (t == 0) ? 0 : lds[t - 1];
    for (int i = 0; i < CH; i++) {
        int idx = base + i;
        if (idx < NN) {
            row_ptr[idx] = run;
            cursor[idx] = run;
            run += cnt[idx];
        }
    }
    if (t == 255) row_ptr[NN] = lds[255];
}

__global__ void scatter_kernel(const int* __restrict__ ei, const float* __restrict__ ew,
                               int* __restrict__ cursor, int* __restrict__ esrc,
                               float* __restrict__ ews) {
    int e = blockIdx.x * 256 + threadIdx.x;
    if (e >= NE) return;
    int d = ei[NE + e];
    int pos = atomicAdd(&cursor[d], 1);
    esrc[pos] = ei[e];
    ews[pos] = ew[e];
}

// ---------------- GEMM: C = act(A[M,128] @ W[128,128] + b) ----------------
// blockIdx.y selects one of two independent (A,W,b,C) problems (msg/self pairing).
// A tile staged in LDS (16 KiB); W read from global (64 KiB f32, L2-resident,
// shared by all blocks) — f32 W in LDS would blow the 64 KiB static limit.

__global__ __launch_bounds__(256) void gemm_pair_kernel(
    const float* __restrict__ A0, const float* __restrict__ A1,
    const float* __restrict__ W0, const float* __restrict__ b0, float* __restrict__ C0,
    const float* __restrict__ W1, const float* __restrict__ b1, float* __restrict__ C1,
    int M, int do_relu) {
    const float* A = blockIdx.y ? A1 : A0;
    const float* W = blockIdx.y ? W1 : W0;
    const float* bias = blockIdx.y ? b1 : b0;
    float* C = blockIdx.y ? C1 : C0;

    __shared__ float Al[32][D];    // 16 KiB A tile
    int t = threadIdx.x;
    int row0 = blockIdx.x * 32;
    for (int i = t; i < 32 * D; i += 256) {
        int r = row0 + (i >> 7);
        Al[i >> 7][i & 127] = (r < M) ? A[r * D + (i & 127)] : 0.f;
    }
    __syncthreads();

    int tc = t & 63;   // lane -> cols {tc, tc+64}
    int tg = t >> 6;   // wave id -> rows tg*8 .. tg*8+7 (A reads broadcast within wave)
    float acc0[8] = {0, 0, 0, 0, 0, 0, 0, 0};
    float acc1[8] = {0, 0, 0, 0, 0, 0, 0, 0};
#pragma unroll 4
    for (int k = 0; k < D; k += 4) {
        float w0[4], w1[4];
#pragma unroll
        for (int kk = 0; kk < 4; kk++) {
            w0[kk] = W[(k + kk) * D + tc];         // coalesced, L2-hit
            w1[kk] = W[(k + kk) * D + tc + 64];
        }
#pragma unroll
        for (int i = 0; i < 8; i++) {
            float4 a = *(const float4*)&Al[tg * 8 + i][k];  // 16B-aligned (k%4==0)
            acc0[i] = fmaf(a.x, w0[0], fmaf(a.y, w0[1], fmaf(a.z, w0[2], fmaf(a.w, w0[3], acc0[i]))));
            acc1[i] = fmaf(a.x, w1[0], fmaf(a.y, w1[1], fmaf(a.z, w1[2], fmaf(a.w, w1[3], acc1[i]))));
        }
    }
    float bv0 = bias[tc];
    float bv1 = bias[tc + 64];
    for (int i = 0; i < 8; i++) {
        int r = row0 + tg * 8 + i;
        if (r < M) {
            float v0 = acc0[i] + bv0;
            float v1 = acc1[i] + bv1;
            if (do_relu) { v0 = fmaxf(v0, 0.f); v1 = fmaxf(v1, 0.f); }
            C[r * D + tc] = v0;
            C[r * D + tc + 64] = v1;
        }
    }
}

// ---------------- CSR aggregate: one wave per dst node ----------------
// h_next = relu(sum_e w_e * Mmsg[src_e] + Mself[dst]); written to the stacked
// output slice, which doubles as the next layer's h.

__global__ __launch_bounds__(256) void aggregate_kernel(
    const float* __restrict__ Mmsg, const float* __restrict__ Mself,
    const int* __restrict__ row_ptr, const int* __restrict__ esrc,
    const float* __restrict__ ews, float* __restrict__ stacked_out) {
    int wid = (blockIdx.x * 256 + threadIdx.x) >> 6;
    int lane = threadIdx.x & 63;
    if (wid >= NN) return;
    int beg = row_ptr[wid], end = row_ptr[wid + 1];
    float a0 = 0.f, a1 = 0.f;
    for (int j = beg; j < end; j++) {
        int s = esrc[j];        // wave-uniform broadcast load
        float w = ews[j];
        a0 = fmaf(w, Mmsg[s * D + lane], a0);        // 256B contiguous gather
        a1 = fmaf(w, Mmsg[s * D + lane + 64], a1);
    }
    stacked_out[wid * D + lane] = fmaxf(a0 + Mself[wid * D + lane], 0.f);
    stacked_out[wid * D + lane + 64] = fmaxf(a1 + Mself[wid * D + lane + 64], 0.f);
}

// ---------------- scoring: s[n] = T[n,:] . w2 + b2 (one wave per node) ----------------

__global__ __launch_bounds__(256) void score_reduce_kernel(const float* __restrict__ T,
                                                           const float* __restrict__ w2,
                                                           const float* __restrict__ b2,
                                                           float* __restrict__ scores) {
    int wid = (blockIdx.x * 256 + threadIdx.x) >> 6;
    int lane = threadIdx.x & 63;
    if (wid >= NN) return;
    float v = T[wid * D + lane] * w2[lane] + T[wid * D + lane + 64] * w2[lane + 64];
    for (int off = 32; off; off >>= 1) v += __shfl_down(v, off);
    if (lane == 0) scores[wid] = v + b2[0];
}

// ---------------- softmax over layers + weighted sum ----------------

__global__ void finalize_kernel(const float* __restrict__ scores, const float* __restrict__ st,
                                float* __restrict__ out, float* __restrict__ lw_out) {
    int n = blockIdx.x;
    int c = threadIdx.x;  // 128 threads
    float s0 = scores[n], s1 = scores[NN + n], s2 = scores[2 * NN + n];
    float m = fmaxf(s0, fmaxf(s1, s2));
    float e0 = expf(s0 - m), e1 = expf(s1 - m), e2 = expf(s2 - m);
    float inv = 1.f / (e0 + e1 + e2);
    float w0 = e0 * inv, w1 = e1 * inv, w2 = e2 * inv;
    float v = w0 * st[n * D + c] + w1 * st[NF + n * D + c] + w2 * st[2 * NF + n * D + c];
    out[n * D + c] = v;
    if (c < 3) {
        float w = (c == 0) ? w0 : ((c == 1) ? w1 : w2);
        lw_out[c * NN + n] = w;
    }
}

extern "C" void kernel_launch(void* const* d_in, const int* in_sizes, int n_in,
                              void* d_out, int out_size, void* d_ws, size_t ws_size,
                              hipStream_t stream) {
    const float* x = (const float*)d_in[0];
    const int* ei = (const int*)d_in[1];
    const float* conf = (const float*)d_in[2];
    const float* msg_W1 = (const float*)d_in[3];
    const float* msg_b1 = (const float*)d_in[4];
    const float* msg_W2 = (const float*)d_in[5];
    const float* msg_b2 = (const float*)d_in[6];
    const float* self_W1 = (const float*)d_in[7];
    const float* self_b1 = (const float*)d_in[8];
    const float* self_W2 = (const float*)d_in[9];
    const float* self_b2 = (const float*)d_in[10];
    const float* score_W1 = (const float*)d_in[11];
    const float* score_b1 = (const float*)d_in[12];
    const float* score_W2 = (const float*)d_in[13];
    const float* score_b2 = (const float*)d_in[14];

    float* out = (float*)d_out;                 // [NN,D] output
    float* out_stacked = out + NF;              // [3,NN,D]
    float* out_lw = out + 4 * (size_t)NF;       // [3,NN]

    float* w = (float*)d_ws;
    float* Mmsg = w;                            // NF
    float* Mself = w + 1 * (size_t)NF;
    float* T = w + 2 * (size_t)NF;
    float* T2 = w + 3 * (size_t)NF;
    float* edge_w = w + 4 * (size_t)NF;         // NE
    float* ews = edge_w + NE;                   // NE (dst-sorted)
    float* scores = ews + NE;                   // 3*NN
    int* esrc = (int*)(scores + 3 * NN);        // NE
    int* row_ptr = esrc + NE;                   // NN+1
    int* cnt = row_ptr + NN + 1;                // NN
    int* cursor = cnt + NN;                     // NN

    const int GE = (NE + 255) / 256;
    const int GN = (NN + 255) / 256;
    const int GX = (NN * 64 + 255) / 256;       // one wave per node
    const int GB = (NN + 31) / 32;              // gemm row-blocks

    zero_cnt_kernel<<<GN, 256, 0, stream>>>(cnt);
    edge_prep_kernel<<<GE, 256, 0, stream>>>(ei, conf, edge_w, cnt);
    scan_kernel<<<1, 256, 0, stream>>>(cnt, row_ptr, cursor);
    scatter_kernel<<<GE, 256, 0, stream>>>(ei, edge_w, cursor, esrc, ews);

    for (int l = 0; l < 3; l++) {
        const float* mW1 = msg_W1 + (size_t)l * D * D;
        const float* mW2 = msg_W2 + (size_t)l * D * D;
        const float* sW1 = self_W1 + (size_t)l * D * D;
        const float* sW2 = self_W2 + (size_t)l * D * D;
        const float* mb1 = msg_b1 + (size_t)l * D;
        const float* mb2 = msg_b2 + (size_t)l * D;
        const float* sb1 = self_b1 + (size_t)l * D;
        const float* sb2 = self_b2 + (size_t)l * D;
        const float* h_in = (l == 0) ? x : out_stacked + (size_t)(l - 1) * NF;

        gemm_pair_kernel<<<dim3(GB, 2), 256, 0, stream>>>(
            h_in, h_in, mW1, mb1, T, sW1, sb1, T2, NN, 1);
        gemm_pair_kernel<<<dim3(GB, 2), 256, 0, stream>>>(
            T, T2, mW2, mb2, Mmsg, sW2, sb2, Mself, NN, 0);
        aggregate_kernel<<<GX, 256, 0, stream>>>(Mmsg, Mself, row_ptr, esrc, ews,
                                                 out_stacked + (size_t)l * NF);
    }

    for (int l = 0; l < 3; l++) {
        const float* st_l = out_stacked + (size_t)l * NF;
        gemm_pair_kernel<<<dim3(GB, 1), 256, 0, stream>>>(
            st_l, st_l, score_W1, score_b1, T, score_W1, score_b1, T, NN, 1);
        score_reduce_kernel<<<GX, 256, 0, stream>>>(T, score_W2, score_b2, scores + (size_t)l * NN);
    }

    finalize_kernel<<<NN, 128, 0, stream>>>(scores, out_stacked, out, out_lw);
}

// Round 3
// 536.884 us; speedup vs baseline: 1.2441x; 1.2441x over previous
//
#include <hip/hip_runtime.h>

#define NN 10000
#define NE 640000
#define D 128
#define NF (NN * D)

// ---------------- CSR build ----------------

__global__ void zero_cnt_kernel(int* __restrict__ cnt) {
    int i = blockIdx.x * 256 + threadIdx.x;
    if (i < NN) cnt[i] = 0;
}

__global__ void hist_kernel(const int* __restrict__ ei, int* __restrict__ cnt) {
    int e = blockIdx.x * 256 + threadIdx.x;
    if (e < NE) atomicAdd(&cnt[ei[NE + e]], 1);
}

__global__ void scan_kernel(const int* __restrict__ cnt, int* __restrict__ row_ptr,
                            int* __restrict__ cursor) {
    __shared__ int lds[256];
    int t = threadIdx.x;
    const int CH = (NN + 255) / 256;  // 40
    int base = t * CH;
    int s = 0;
    for (int i = 0; i < CH; i++) {
        int idx = base + i;
        if (idx < NN) s += cnt[idx];
    }
    lds[t] = s;
    __syncthreads();
    for (int off = 1; off < 256; off <<= 1) {
        int v = (t >= off) ? lds[t - off] : 0;
        __syncthreads();
        lds[t] += v;
        __syncthreads();
    }
    int run = (t == 0) ? 0 : lds[t - 1];
    for (int i = 0; i < CH; i++) {
        int idx = base + i;
        if (idx < NN) {
            row_ptr[idx] = run;
            cursor[idx] = run;
            run += cnt[idx];
        }
    }
    if (t == 255) row_ptr[NN] = lds[255];
}

__global__ void scatter_kernel(const int* __restrict__ ei, const float* __restrict__ conf,
                               int* __restrict__ cursor, int* __restrict__ esrc,
                               float* __restrict__ ews) {
    int e = blockIdx.x * 256 + threadIdx.x;
    if (e >= NE) return;
    int s = ei[e];
    int d = ei[NE + e];
    int pos = atomicAdd(&cursor[d], 1);
    esrc[pos] = s;
    ews[pos] = expf(-fabsf(conf[s] - conf[d]));  // recompute here: saves edge_w round-trip
}

// ---------------- fused 2-layer MLP: C = (relu(A@W1+b1))@W2 + b2 ----------------
// blockIdx.y picks problem (msg / self). T tile lives in LDS — no global round trip.
// Output C is written in PAIRED layout: features (c, c+64) adjacent as float2 at
// C[r*128 + 2*c], so the aggregate gather is one dwordx2 per edge.

__global__ __launch_bounds__(256) void mlp_pair_kernel(
    const float* __restrict__ A,
    const float* __restrict__ W1a, const float* __restrict__ b1a,
    const float* __restrict__ W2a, const float* __restrict__ b2a, float* __restrict__ Ca,
    const float* __restrict__ W1b, const float* __restrict__ b1b,
    const float* __restrict__ W2b, const float* __restrict__ b2b, float* __restrict__ Cb,
    int M) {
    const float* W1 = blockIdx.y ? W1b : W1a;
    const float* b1 = blockIdx.y ? b1b : b1a;
    const float* W2 = blockIdx.y ? W2b : W2a;
    const float* b2 = blockIdx.y ? b2b : b2a;
    float* C = blockIdx.y ? Cb : Ca;

    __shared__ float Al[32][D];   // 16 KiB
    __shared__ float Tl[32][D];   // 16 KiB
    int t = threadIdx.x;
    int row0 = blockIdx.x * 32;
    for (int i = t; i < 32 * D; i += 256) {
        int r = row0 + (i >> 7);
        Al[i >> 7][i & 127] = (r < M) ? A[(size_t)r * D + (i & 127)] : 0.f;
    }
    __syncthreads();

    int tc = t & 63;   // cols {tc, tc+64}
    int tg = t >> 6;   // rows tg*8 .. tg*8+7 (A reads broadcast within wave)

    // ---- stage 1 ----
    float acc0[8] = {0, 0, 0, 0, 0, 0, 0, 0};
    float acc1[8] = {0, 0, 0, 0, 0, 0, 0, 0};
#pragma unroll 4
    for (int k = 0; k < D; k += 4) {
        float w0[4], w1[4];
#pragma unroll
        for (int kk = 0; kk < 4; kk++) {
            w0[kk] = W1[(k + kk) * D + tc];
            w1[kk] = W1[(k + kk) * D + tc + 64];
        }
#pragma unroll
        for (int i = 0; i < 8; i++) {
            float4 a = *(const float4*)&Al[tg * 8 + i][k];
            acc0[i] = fmaf(a.x, w0[0], fmaf(a.y, w0[1], fmaf(a.z, w0[2], fmaf(a.w, w0[3], acc0[i]))));
            acc1[i] = fmaf(a.x, w1[0], fmaf(a.y, w1[1], fmaf(a.z, w1[2], fmaf(a.w, w1[3], acc1[i]))));
        }
    }
    float bv0 = b1[tc], bv1 = b1[tc + 64];
#pragma unroll
    for (int i = 0; i < 8; i++) {
        Tl[tg * 8 + i][tc] = fmaxf(acc0[i] + bv0, 0.f);
        Tl[tg * 8 + i][tc + 64] = fmaxf(acc1[i] + bv1, 0.f);
    }
    __syncthreads();

    // ---- stage 2 ----
    float d0[8] = {0, 0, 0, 0, 0, 0, 0, 0};
    float d1[8] = {0, 0, 0, 0, 0, 0, 0, 0};
#pragma unroll 4
    for (int k = 0; k < D; k += 4) {
        float w0[4], w1[4];
#pragma unroll
        for (int kk = 0; kk < 4; kk++) {
            w0[kk] = W2[(k + kk) * D + tc];
            w1[kk] = W2[(k + kk) * D + tc + 64];
        }
#pragma unroll
        for (int i = 0; i < 8; i++) {
            float4 a = *(const float4*)&Tl[tg * 8 + i][k];
            d0[i] = fmaf(a.x, w0[0], fmaf(a.y, w0[1], fmaf(a.z, w0[2], fmaf(a.w, w0[3], d0[i]))));
            d1[i] = fmaf(a.x, w1[0], fmaf(a.y, w1[1], fmaf(a.z, w1[2], fmaf(a.w, w1[3], d1[i]))));
        }
    }
    float cb0 = b2[tc], cb1 = b2[tc + 64];
#pragma unroll
    for (int i = 0; i < 8; i++) {
        int r = row0 + tg * 8 + i;
        if (r < M) {
            float2 v;
            v.x = d0[i] + cb0;   // feature tc
            v.y = d1[i] + cb1;   // feature tc+64
            *(float2*)&C[(size_t)r * D + 2 * tc] = v;  // paired layout, coalesced dwordx2
        }
    }
}

// ---------------- CSR aggregate: one block (4 waves) per dst node ----------------
// Mmsg/Mself in paired layout; output written canonical (it's the graded stacked slice
// and the next layer's GEMM input).

__global__ __launch_bounds__(256) void aggregate_kernel(
    const float2* __restrict__ Mmsg2, const float* __restrict__ Mself,
    const int* __restrict__ row_ptr, const int* __restrict__ esrc,
    const float* __restrict__ ews, float* __restrict__ out) {
    int n = blockIdx.x;
    int t = threadIdx.x;
    int w = t >> 6, lane = t & 63;
    int beg = row_ptr[n], end = row_ptr[n + 1];
    float a0 = 0.f, a1 = 0.f;
    int j = beg + w;
    int s = 0;
    float wt = 0.f;
    if (j < end) { s = esrc[j]; wt = ews[j]; }  // prefetch
    while (j < end) {
        int jn = j + 4;
        int sn = 0;
        float wtn = 0.f;
        if (jn < end) { sn = esrc[jn]; wtn = ews[jn]; }  // next iter's meta in flight
        float2 g = Mmsg2[(size_t)s * 64 + lane];         // 512 B/wave, one dwordx2
        a0 = fmaf(wt, g.x, a0);
        a1 = fmaf(wt, g.y, a1);
        j = jn; s = sn; wt = wtn;
    }
    __shared__ float2 part[4][64];
    part[w][lane] = make_float2(a0, a1);
    __syncthreads();
    if (t < D) {
        // paired index t -> canonical feature c
        int c = (t >> 1) + 64 * (t & 1);
        const float* p = &part[0][0].x;
        float v = p[t] + p[D + t] + p[2 * D + t] + p[3 * D + t] + Mself[(size_t)n * D + t];
        out[(size_t)n * D + c] = fmaxf(v, 0.f);
    }
}

// ---------------- fused scoring: all 3 layers in one dispatch ----------------
// scores[l][n] = relu(stacked_l @ W1 + b1) . w2 + b2

__global__ __launch_bounds__(256) void score_kernel(
    const float* __restrict__ stacked, const float* __restrict__ W1,
    const float* __restrict__ b1, const float* __restrict__ w2,
    const float* __restrict__ b2, float* __restrict__ scores) {
    int l = blockIdx.y;
    const float* A = stacked + (size_t)l * NF;
    __shared__ float Al[32][D];
    __shared__ float Tl[32][D];
    int t = threadIdx.x;
    int row0 = blockIdx.x * 32;
    for (int i = t; i < 32 * D; i += 256) {
        int r = row0 + (i >> 7);
        Al[i >> 7][i & 127] = (r < NN) ? A[(size_t)r * D + (i & 127)] : 0.f;
    }
    __syncthreads();

    int tc = t & 63, tg = t >> 6;
    float acc0[8] = {0, 0, 0, 0, 0, 0, 0, 0};
    float acc1[8] = {0, 0, 0, 0, 0, 0, 0, 0};
#pragma unroll 4
    for (int k = 0; k < D; k += 4) {
        float w0[4], w1[4];
#pragma unroll
        for (int kk = 0; kk < 4; kk++) {
            w0[kk] = W1[(k + kk) * D + tc];
            w1[kk] = W1[(k + kk) * D + tc + 64];
        }
#pragma unroll
        for (int i = 0; i < 8; i++) {
            float4 a = *(const float4*)&Al[tg * 8 + i][k];
            acc0[i] = fmaf(a.x, w0[0], fmaf(a.y, w0[1], fmaf(a.z, w0[2], fmaf(a.w, w0[3], acc0[i]))));
            acc1[i] = fmaf(a.x, w1[0], fmaf(a.y, w1[1], fmaf(a.z, w1[2], fmaf(a.w, w1[3], acc1[i]))));
        }
    }
    float bv0 = b1[tc], bv1 = b1[tc + 64];
#pragma unroll
    for (int i = 0; i < 8; i++) {
        Tl[tg * 8 + i][tc] = fmaxf(acc0[i] + bv0, 0.f);
        Tl[tg * 8 + i][tc + 64] = fmaxf(acc1[i] + bv1, 0.f);
    }
    __syncthreads();

    float w2a = w2[tc], w2b = w2[tc + 64];
    float bb = b2[0];
    for (int i = 0; i < 8; i++) {
        int r = tg * 8 + i;
        float v = Tl[r][tc] * w2a + Tl[r][tc + 64] * w2b;
#pragma unroll
        for (int off = 32; off; off >>= 1) v += __shfl_down(v, off);
        int rr = row0 + r;
        if (tc == 0 && rr < NN) scores[l * NN + rr] = v + bb;
    }
}

// ---------------- softmax over layers + weighted sum ----------------

__global__ void finalize_kernel(const float* __restrict__ scores, const float* __restrict__ st,
                                float* __restrict__ out, float* __restrict__ lw_out) {
    int n = blockIdx.x;
    int c = threadIdx.x;  // 128 threads
    float s0 = scores[n], s1 = scores[NN + n], s2 = scores[2 * NN + n];
    float m = fmaxf(s0, fmaxf(s1, s2));
    float e0 = expf(s0 - m), e1 = expf(s1 - m), e2 = expf(s2 - m);
    float inv = 1.f / (e0 + e1 + e2);
    float w0 = e0 * inv, w1 = e1 * inv, w2 = e2 * inv;
    float v = w0 * st[n * D + c] + w1 * st[NF + n * D + c] + w2 * st[2 * NF + n * D + c];
    out[n * D + c] = v;
    if (c < 3) {
        float w = (c == 0) ? w0 : ((c == 1) ? w1 : w2);
        lw_out[c * NN + n] = w;
    }
}

extern "C" void kernel_launch(void* const* d_in, const int* in_sizes, int n_in,
                              void* d_out, int out_size, void* d_ws, size_t ws_size,
                              hipStream_t stream) {
    const float* x = (const float*)d_in[0];
    const int* ei = (const int*)d_in[1];
    const float* conf = (const float*)d_in[2];
    const float* msg_W1 = (const float*)d_in[3];
    const float* msg_b1 = (const float*)d_in[4];
    const float* msg_W2 = (const float*)d_in[5];
    const float* msg_b2 = (const float*)d_in[6];
    const float* self_W1 = (const float*)d_in[7];
    const float* self_b1 = (const float*)d_in[8];
    const float* self_W2 = (const float*)d_in[9];
    const float* self_b2 = (const float*)d_in[10];
    const float* score_W1 = (const float*)d_in[11];
    const float* score_b1 = (const float*)d_in[12];
    const float* score_W2 = (const float*)d_in[13];
    const float* score_b2 = (const float*)d_in[14];

    float* out = (float*)d_out;                 // [NN,D]
    float* out_stacked = out + NF;              // [3,NN,D]  (canonical, graded)
    float* out_lw = out + 4 * (size_t)NF;       // [3,NN]

    float* w = (float*)d_ws;
    float* Mmsg = w;                            // NF (paired layout)
    float* Mself = w + 1 * (size_t)NF;          // NF (paired layout)
    float* ews = w + 2 * (size_t)NF;            // NE (dst-sorted)
    float* scores = ews + NE;                   // 3*NN
    int* esrc = (int*)(scores + 3 * NN);        // NE
    int* row_ptr = esrc + NE;                   // NN+1
    int* cnt = row_ptr + NN + 1;                // NN
    int* cursor = cnt + NN;                     // NN

    const int GE = (NE + 255) / 256;
    const int GN = (NN + 255) / 256;
    const int GB = (NN + 31) / 32;              // 313 row-blocks

    zero_cnt_kernel<<<GN, 256, 0, stream>>>(cnt);
    hist_kernel<<<GE, 256, 0, stream>>>(ei, cnt);
    scan_kernel<<<1, 256, 0, stream>>>(cnt, row_ptr, cursor);
    scatter_kernel<<<GE, 256, 0, stream>>>(ei, conf, cursor, esrc, ews);

    for (int l = 0; l < 3; l++) {
        const float* h_in = (l == 0) ? x : out_stacked + (size_t)(l - 1) * NF;
        mlp_pair_kernel<<<dim3(GB, 2), 256, 0, stream>>>(
            h_in,
            msg_W1 + (size_t)l * D * D, msg_b1 + (size_t)l * D,
            msg_W2 + (size_t)l * D * D, msg_b2 + (size_t)l * D, Mmsg,
            self_W1 + (size_t)l * D * D, self_b1 + (size_t)l * D,
            self_W2 + (size_t)l * D * D, self_b2 + (size_t)l * D, Mself,
            NN);
        aggregate_kernel<<<NN, 256, 0, stream>>>((const float2*)Mmsg, Mself, row_ptr,
                                                 esrc, ews, out_stacked + (size_t)l * NF);
    }

    score_kernel<<<dim3(GB, 3), 256, 0, stream>>>(out_stacked, score_W1, score_b1,
                                                  score_W2, score_b2, scores);
    finalize_kernel<<<NN, 128, 0, stream>>>(scores, out_stacked, out, out_lw);
}